// Round 5
// baseline (55.018 us; speedup 1.0000x reference)
//
#include <hip/hip_runtime.h>
#include <math.h>

#define BB 4
#define TT 4096
#define CC 1024
#define HS 64
#define WIN 512
#define NROW (BB*TT)

typedef float f32x4 __attribute__((ext_vector_type(4)));
typedef short bf16x8 __attribute__((ext_vector_type(8)));

#define MFMA16(a, b, c) __builtin_amdgcn_mfma_f32_16x16x32_bf16((a), (b), (c), 0, 0, 0)

__device__ inline unsigned short f2b(float f) {
  union { float f; unsigned u; } v; v.f = f;
  unsigned r = v.u + 0x7FFFu + ((v.u >> 16) & 1u);   // round-nearest-even
  return (unsigned short)(r >> 16);
}

// ---------------- pack W into MFMA B-fragment order (bf16) ----------------
// wp flat index: ((kt*12 + nb)*64 + lane)*8 + j
// holds W[k = kt*32 + (lane>>4)*8 + j][n = nb*16 + (lane&15)],
// n: 0..63 = w_query, 64..127 = w_key, 128..191 = w_value
__global__ __launch_bounds__(256) void pack_w_kernel(
    const float* __restrict__ wq, const float* __restrict__ wk,
    const float* __restrict__ wv, unsigned short* __restrict__ wp)
{
  int t = blockIdx.x * 256 + threadIdx.x;   // 49152 threads
  int kg = t / 48;                          // 0..1023  (k index)
  int nq = t % 48;                          // 4-col group
  int n0 = nq * 4;
  int m  = n0 >> 6;
  int c  = n0 & 63;
  const float* w = (m == 0) ? wq : (m == 1) ? wk : wv;
  float4 v = *(const float4*)&w[(size_t)kg * HS + c];
  int kt = kg >> 5;
  int hi = (kg >> 3) & 3;
  int j  = kg & 7;
  float vals[4] = {v.x, v.y, v.z, v.w};
  #pragma unroll
  for (int i = 0; i < 4; ++i) {
    int n  = n0 + i;
    int nb = n >> 4;
    int rl = n & 15;
    int lane = hi * 16 + rl;
    wp[((size_t)(kt * 12 + nb) * 64 + lane) * 8 + j] = f2b(vals[i]);
  }
}

// ---------------- Projection via MFMA: [q|k|v] = x @ W ----------------
// grid 1024 blocks x 256 threads (4 waves = 2 colhalves x 2 khalves).
// Block = one 16-row tile. Wave = 16 rows x 96 cols x K/2 (6 MFMA col-blocks,
// 16 kt steps). khalf=1 accs reduced into khalf=0 via LDS. Register-pipelined:
// x 4 kt deep, wp 2 kt deep.
__global__ __launch_bounds__(256) void proj_mfma_kernel(
    const float* __restrict__ x, const unsigned short* __restrict__ wp,
    unsigned short* __restrict__ q_ws, unsigned short* __restrict__ k_ws,
    unsigned short* __restrict__ vt_ws)
{
  __shared__ float lds_red[2][64][24];   // 12 KB: [colhalf][lane][6*f32x4]

  const int tid = threadIdx.x;
  const int l   = tid & 63;
  const int wid = tid >> 6;
  const int colhalf = wid & 1;
  const int khalf   = wid >> 1;
  const int r0  = blockIdx.x * 16;
  const int rl  = l & 15;
  const int hi  = l >> 4;
  const int nb0 = colhalf * 6;

  f32x4 acc[6];
  #pragma unroll
  for (int i = 0; i < 6; ++i) acc[i] = (f32x4){0.f, 0.f, 0.f, 0.f};

  const float* xrow = x + (size_t)(r0 + rl) * CC + khalf * 512 + hi * 8;
  const unsigned short* wpl = wp + (size_t)(khalf * 16 * 12 + nb0) * 512 + l * 8;

#define LOADX(D0v, D1v, KTv) { D0v = *(const float4*)(xrow + (KTv) * 32); \
                               D1v = *(const float4*)(xrow + (KTv) * 32 + 4); }
#define LOADW(DSTv, KTv) { _Pragma("unroll") \
    for (int jj = 0; jj < 6; ++jj) DSTv[jj] = *(const bf16x8*)(wpl + (size_t)(KTv) * 6144 + jj * 512); }
#define COMPUTE(A0v, A1v, WFv) { bf16x8 af; \
    af[0] = (short)f2b((A0v).x); af[1] = (short)f2b((A0v).y); \
    af[2] = (short)f2b((A0v).z); af[3] = (short)f2b((A0v).w); \
    af[4] = (short)f2b((A1v).x); af[5] = (short)f2b((A1v).y); \
    af[6] = (short)f2b((A1v).z); af[7] = (short)f2b((A1v).w); \
    _Pragma("unroll") \
    for (int jj = 0; jj < 6; ++jj) acc[jj] = MFMA16(af, WFv[jj], acc[jj]); }

  float4 xA0, xA1, xB0, xB1, xC0, xC1, xD0, xD1;
  bf16x8 wP[6], wQ[6];

  LOADX(xA0, xA1, 0) LOADX(xB0, xB1, 1) LOADX(xC0, xC1, 2) LOADX(xD0, xD1, 3)
  LOADW(wP, 0) LOADW(wQ, 1)

  for (int kt = 0; kt < 16; kt += 4) {
    COMPUTE(xA0, xA1, wP)
    if (kt + 4 < 16) { LOADX(xA0, xA1, kt + 4) }
    if (kt + 2 < 16) { LOADW(wP, kt + 2) }
    COMPUTE(xB0, xB1, wQ)
    if (kt + 5 < 16) { LOADX(xB0, xB1, kt + 5) }
    if (kt + 3 < 16) { LOADW(wQ, kt + 3) }
    COMPUTE(xC0, xC1, wP)
    if (kt + 6 < 16) { LOADX(xC0, xC1, kt + 6) }
    if (kt + 4 < 16) { LOADW(wP, kt + 4) }
    COMPUTE(xD0, xD1, wQ)
    if (kt + 7 < 16) { LOADX(xD0, xD1, kt + 7) }
    if (kt + 5 < 16) { LOADW(wQ, kt + 5) }
  }
#undef LOADX
#undef LOADW
#undef COMPUTE

  // ---- K-halves reduction through LDS ----
  if (khalf == 1) {
    #pragma unroll
    for (int j = 0; j < 6; ++j)
      *(f32x4*)&lds_red[colhalf][l][j * 4] = acc[j];
  }
  __syncthreads();
  if (khalf == 1) return;
  #pragma unroll
  for (int j = 0; j < 6; ++j) {
    f32x4 o = *(const f32x4*)&lds_red[colhalf][l][j * 4];
    acc[j][0] += o[0]; acc[j][1] += o[1]; acc[j][2] += o[2]; acc[j][3] += o[3];
  }

  // store: nb = nb0 + j; nb 0..3 -> q, 4..7 -> k, 8..11 -> v (transposed)
  #pragma unroll
  for (int j = 0; j < 6; ++j) {
    int nb = nb0 + j;
    if (nb < 8) {
      unsigned short* dst = (nb < 4) ? q_ws : k_ws;
      int c = (nb & 3) * 16 + rl;
      #pragma unroll
      for (int r = 0; r < 4; ++r) {
        int row = r0 + hi * 4 + r;
        dst[(size_t)row * HS + c] = f2b(acc[j][r]);
      }
    } else {
      int ch   = r0 >> 6;
      int key0 = (r0 & 63) + hi * 4;
      int d = (nb - 8) * 16 + rl;
      unsigned u0 = (unsigned)f2b(acc[j][0]) | ((unsigned)f2b(acc[j][1]) << 16);
      unsigned u1 = (unsigned)f2b(acc[j][2]) | ((unsigned)f2b(acc[j][3]) << 16);
      uint2 uu; uu.x = u0; uu.y = u1;
      *(uint2*)(vt_ws + (size_t)ch * 4096 + d * 64 + key0) = uu;
    }
  }
}

// ---------------- Sliding-window flash attention via MFMA ----------------
// grid 256 blocks (b, 64-q tile) x 256 threads (4 waves, 16 q-rows each).
// Swapped QK^T (S^T = K @ Q^T) -> softmax lane-local; P via wave-private LDS;
// PV with V^T staged swizzled.
__global__ __launch_bounds__(256) void attn_mfma_kernel(
    const unsigned short* __restrict__ q_ws, const unsigned short* __restrict__ k_ws,
    const unsigned short* __restrict__ vt_ws, float* __restrict__ out)
{
  __shared__ uint4 smem4[1600];                 // 25600 B
  unsigned char* smem = (unsigned char*)smem4;  // K:[0,8K) Vt:[8K,16K) P:16K+

  const int tid = threadIdx.x;
  const int l   = tid & 63;
  const int wid = tid >> 6;
  const int rl  = l & 15;
  const int hi  = l >> 4;
  const int b   = blockIdx.x >> 6;
  const int qt  = blockIdx.x & 63;
  const int t0  = qt * 64;
  const int t0w = t0 + wid * 16;

  // Q B-fragments (held in registers): lane = q row t0w+rl, d = hi*8+j (+32)
  const unsigned short* qrow = q_ws + (size_t)(b * TT + t0w + rl) * HS;
  bf16x8 qb0 = *(const bf16x8*)(qrow + hi * 8);
  bf16x8 qb1 = *(const bf16x8*)(qrow + 32 + hi * 8);

  f32x4 oacc[4];
  #pragma unroll
  for (int i = 0; i < 4; ++i) oacc[i] = (f32x4){0.f, 0.f, 0.f, 0.f};
  float m_run = -INFINITY, l_run = 0.f;

  int s_lo = t0 - WIN; if (s_lo < 0) s_lo = 0;
  unsigned char* pbase = smem + 16384 + wid * 2304 + rl * 144;

  for (int sc = s_lo; sc < t0 + 64; sc += 64) {
    __syncthreads();
    // ---- stage K and Vt chunk (64x64 bf16 each), XOR-swizzled rows ----
    {
      const unsigned short* kg = k_ws + (size_t)(b * TT + sc) * HS;
      const unsigned short* vg = vt_ws + (size_t)((b * TT + sc) >> 6) * 4096;
      #pragma unroll
      for (int i = 0; i < 2; ++i) {
        int idx = tid + i * 256;
        int row = idx >> 3;
        int c16 = idx & 7;
        uint4 kv = *(const uint4*)(kg + row * 64 + c16 * 8);
        uint4 vv = *(const uint4*)(vg + row * 64 + c16 * 8);
        *(uint4*)(smem + row * 128 + ((c16 ^ (row & 7)) * 16)) = kv;
        *(uint4*)(smem + 8192 + row * 128 + ((c16 ^ (row & 7)) * 16)) = vv;
      }
    }
    __syncthreads();

    // ---- S^T = K @ Q^T : 4 key-block fragments ----
    f32x4 sacc[4];
    #pragma unroll
    for (int i = 0; i < 4; ++i) sacc[i] = (f32x4){0.f, 0.f, 0.f, 0.f};
    #pragma unroll
    for (int kb = 0; kb < 4; ++kb) {
      int row = kb * 16 + rl;
      unsigned char* kr = smem + row * 128;
      bf16x8 k0 = *(const bf16x8*)(kr + (((hi) ^ (row & 7)) * 16));
      bf16x8 k1 = *(const bf16x8*)(kr + (((4 + hi) ^ (row & 7)) * 16));
      sacc[kb] = MFMA16(k0, qb0, sacc[kb]);
      sacc[kb] = MFMA16(k1, qb1, sacc[kb]);
    }

    // ---- mask + scale + online softmax (lane owns one q = t0w+rl) ----
    const int tg = t0w + rl;
    float p[16];
    float tm = -INFINITY;
    bool full = (sc + 63 <= t0w) && (sc >= t0w - 496);
    #pragma unroll
    for (int kb = 0; kb < 4; ++kb)
      #pragma unroll
      for (int r = 0; r < 4; ++r) {
        float v = sacc[kb][r] * 0.125f;
        if (!full) {
          int key = sc + kb * 16 + hi * 4 + r;
          int diff = tg - key;
          v = (diff >= 0 && diff < WIN) ? v : -INFINITY;
        }
        p[kb * 4 + r] = v;
        tm = fmaxf(tm, v);
      }
    tm = fmaxf(tm, __shfl_xor(tm, 16));
    tm = fmaxf(tm, __shfl_xor(tm, 32));
    float m_new = fmaxf(m_run, tm);
    float fac  = (m_new == -INFINITY) ? 1.f : __expf(m_run - m_new);
    float msub = (m_new == -INFINITY) ? 0.f : m_new;
    float lsum = 0.f;
    #pragma unroll
    for (int i = 0; i < 16; ++i) { p[i] = __expf(p[i] - msub); lsum += p[i]; }
    lsum += __shfl_xor(lsum, 16);
    lsum += __shfl_xor(lsum, 32);
    l_run = l_run * fac + lsum;
    m_run = m_new;

    // ---- P -> wave-private LDS (row q=rl, stride 144 B) ----
    #pragma unroll
    for (int kb = 0; kb < 4; ++kb) {
      unsigned u0 = (unsigned)f2b(p[kb * 4 + 0]) | ((unsigned)f2b(p[kb * 4 + 1]) << 16);
      unsigned u1 = (unsigned)f2b(p[kb * 4 + 2]) | ((unsigned)f2b(p[kb * 4 + 3]) << 16);
      uint2 uu; uu.x = u0; uu.y = u1;
      *(uint2*)(pbase + kb * 32 + hi * 8) = uu;
    }

    // ---- rescale O by fac (redistribute to PV C-layout q = hi*4+r) ----
    #pragma unroll
    for (int r = 0; r < 4; ++r) {
      float fr = __shfl(fac, (l & 48) | (hi * 4 + r));
      oacc[0][r] *= fr; oacc[1][r] *= fr; oacc[2][r] *= fr; oacc[3][r] *= fr;
    }

    // ---- PV: O[q][d] += P @ V ----
    bf16x8 pa0 = *(const bf16x8*)(pbase + hi * 16);
    bf16x8 pa1 = *(const bf16x8*)(pbase + 64 + hi * 16);
    #pragma unroll
    for (int f = 0; f < 4; ++f) {
      int d = f * 16 + rl;
      unsigned char* vr = smem + 8192 + d * 128;
      bf16x8 v0 = *(const bf16x8*)(vr + (((hi) ^ (d & 7)) * 16));
      bf16x8 v1 = *(const bf16x8*)(vr + (((4 + hi) ^ (d & 7)) * 16));
      oacc[f] = MFMA16(pa0, v0, oacc[f]);
      oacc[f] = MFMA16(pa1, v1, oacc[f]);
    }
  }

  // ---- epilogue: normalize and store f32 ----
  float inv = 1.f / l_run;   // softmax layout (q = rl)
  #pragma unroll
  for (int r = 0; r < 4; ++r) {
    float ir = __shfl(inv, (l & 48) | (hi * 4 + r));
    int row = b * TT + t0w + hi * 4 + r;
    #pragma unroll
    for (int f = 0; f < 4; ++f)
      out[(size_t)row * HS + f * 16 + rl] = oacc[f][r] * ir;
  }
}

extern "C" void kernel_launch(void* const* d_in, const int* in_sizes, int n_in,
                              void* d_out, int out_size, void* d_ws, size_t ws_size,
                              hipStream_t stream) {
  // setup_inputs dict order: x, w_key, w_query, w_value
  const float* x  = (const float*)d_in[0];
  const float* wk = (const float*)d_in[1];
  const float* wq = (const float*)d_in[2];
  const float* wv = (const float*)d_in[3];
  float* out = (float*)d_out;

  unsigned short* wp    = (unsigned short*)d_ws;        // 196608 el = 384 KB
  unsigned short* q_ws  = wp + 196608;                  // 2 MB
  unsigned short* k_ws  = q_ws + (size_t)NROW * HS;     // 2 MB
  unsigned short* vt_ws = k_ws + (size_t)NROW * HS;     // 2 MB

  pack_w_kernel<<<192, 256, 0, stream>>>(wq, wk, wv, wp);
  proj_mfma_kernel<<<NROW / 16, 256, 0, stream>>>(x, wp, q_ws, k_ws, vt_ws);
  attn_mfma_kernel<<<BB * (TT / 64), 256, 0, stream>>>(q_ws, k_ws, vt_ws, out);
}

// Round 6
// 47.135 us; speedup vs baseline: 1.1672x; 1.1672x over previous
//
#include <hip/hip_runtime.h>
#include <hip/hip_bf16.h>
#include <math.h>

#define BB 4
#define TT 4096
#define CC 1024
#define HS 64
#define WIN 512
#define NROW (BB*TT)

typedef float f32x4 __attribute__((ext_vector_type(4)));
typedef short bf16x8 __attribute__((ext_vector_type(8)));

#define MFMA16(a, b, c) __builtin_amdgcn_mfma_f32_16x16x32_bf16((a), (b), (c), 0, 0, 0)

#define GLOAD_LDS(gp, lp) __builtin_amdgcn_global_load_lds( \
    (const __attribute__((address_space(1))) void*)(gp), \
    (__attribute__((address_space(3))) void*)(lp), 16, 0, 0)

__device__ inline unsigned short f2b(float f) {
  union { __hip_bfloat16 h; unsigned short u; } v;
  v.h = __float2bfloat16(f);   // HW RNE convert
  return v.u;
}

// ---------------- pack W into MFMA B-fragment order (bf16) ----------------
// wp flat index: ((kt*12 + nb)*64 + lane)*8 + j
// holds W[k = kt*32 + (lane>>4)*8 + j][n = nb*16 + (lane&15)],
// n: 0..63 = w_query, 64..127 = w_key, 128..191 = w_value
__global__ __launch_bounds__(256) void pack_w_kernel(
    const float* __restrict__ wq, const float* __restrict__ wk,
    const float* __restrict__ wv, unsigned short* __restrict__ wp)
{
  int t = blockIdx.x * 256 + threadIdx.x;   // 49152 threads
  int kg = t / 48;                          // 0..1023  (k index)
  int nq = t % 48;                          // 4-col group
  int n0 = nq * 4;
  int m  = n0 >> 6;
  int c  = n0 & 63;
  const float* w = (m == 0) ? wq : (m == 1) ? wk : wv;
  float4 v = *(const float4*)&w[(size_t)kg * HS + c];
  int kt = kg >> 5;
  int hi = (kg >> 3) & 3;
  int j  = kg & 7;
  float vals[4] = {v.x, v.y, v.z, v.w};
  #pragma unroll
  for (int i = 0; i < 4; ++i) {
    int n  = n0 + i;
    int nb = n >> 4;
    int rl = n & 15;
    int lane = hi * 16 + rl;
    wp[((size_t)(kt * 12 + nb) * 64 + lane) * 8 + j] = f2b(vals[i]);
  }
}

// ---------------- Projection via MFMA: [q|k|v] = x @ W ----------------
// Canonical 2-phase LDS-staged GEMM. 512 blocks x 256 threads (4 waves).
// Block = 32 rows x 192 cols; wave cq owns 32 rows x 48 cols (3 nb).
// K-loop: 16 steps of BK=64. x-tile (8KB f32) + W-slice (24KB bf16) staged
// via global_load_lds (16B/lane), double-buffered; fragment-major LDS layout
// so all ds_read_b128 are consecutive-lane-contiguous (conflict-free).
__global__ __launch_bounds__(256) void proj_mfma_kernel(
    const float* __restrict__ x, const unsigned short* __restrict__ wp,
    unsigned short* __restrict__ q_ws, unsigned short* __restrict__ k_ws,
    unsigned short* __restrict__ vt_ws)
{
  __shared__ unsigned char xbuf[2][8192];    // [buf][slot(512)*16B]
  __shared__ unsigned char wbuf[2][24576];   // [buf][slot(1536)*16B]

  const int tid = threadIdx.x;
  const int l   = tid & 63;
  const int cq  = tid >> 6;     // wave = col quarter (3 nb)
  const int rl  = l & 15;
  const int hi  = l >> 4;
  const int r0  = blockIdx.x * 32;

  f32x4 acc[2][3];
  #pragma unroll
  for (int g = 0; g < 2; ++g)
    #pragma unroll
    for (int j = 0; j < 3; ++j) acc[g][j] = (f32x4){0.f, 0.f, 0.f, 0.f};

  // ---- staging: x slot s (0..511): LDS[s*16] = x[r0 + (s>>7&1)*16 + ((s>>1)&15)]
  //      [ks*64 + (s>>8)*32 + ((s>>5)&3)*8 + (s&1)*4 .. +3]
  //      W slot t (0..1535): LDS[t*16] = wp[ks*12288 + t*8 .. +7]
#define STAGE(KS, BUF) { \
    _Pragma("unroll") \
    for (int r = 0; r < 2; ++r) { \
      int s  = r * 256 + tid; \
      int h2 = s & 1; \
      int lq = (s >> 1) & 63; \
      int f  = s >> 7; \
      int row = r0 + (f & 1) * 16 + (lq & 15); \
      int col = (KS) * 64 + (f >> 1) * 32 + (lq >> 4) * 8 + h2 * 4; \
      GLOAD_LDS(x + (size_t)row * CC + col, &xbuf[BUF][s * 16]); \
    } \
    const unsigned short* wsrc = wp + (size_t)(KS) * 12288; \
    _Pragma("unroll") \
    for (int r = 0; r < 6; ++r) { \
      int t = r * 256 + tid; \
      GLOAD_LDS(wsrc + t * 8, &wbuf[BUF][t * 16]); \
    } }

  STAGE(0, 0)
  asm volatile("s_waitcnt vmcnt(0)" ::: "memory");
  __syncthreads();

  for (int ks = 0; ks < 16; ++ks) {
    const int cur = ks & 1;
    if (ks < 15) STAGE(ks + 1, cur ^ 1)

    // ---- compute from buffers[cur] ----
    #pragma unroll
    for (int ktl = 0; ktl < 2; ++ktl) {
      bf16x8 afr[2];
      #pragma unroll
      for (int g = 0; g < 2; ++g) {
        const float* ap = (const float*)&xbuf[cur][(((ktl * 2 + g) * 64 + l) * 32)];
        f32x4 a0 = *(const f32x4*)ap;
        f32x4 a1 = *(const f32x4*)(ap + 4);
        bf16x8 af;
        af[0] = (short)f2b(a0[0]); af[1] = (short)f2b(a0[1]);
        af[2] = (short)f2b(a0[2]); af[3] = (short)f2b(a0[3]);
        af[4] = (short)f2b(a1[0]); af[5] = (short)f2b(a1[1]);
        af[6] = (short)f2b(a1[2]); af[7] = (short)f2b(a1[3]);
        afr[g] = af;
      }
      #pragma unroll
      for (int j = 0; j < 3; ++j) {
        bf16x8 wf = *(const bf16x8*)&wbuf[cur][((ktl * 12 + cq * 3 + j) * 64 + l) * 16];
        acc[0][j] = MFMA16(afr[0], wf, acc[0][j]);
        acc[1][j] = MFMA16(afr[1], wf, acc[1][j]);
      }
    }

    asm volatile("s_waitcnt vmcnt(0)" ::: "memory");
    __syncthreads();
  }
#undef STAGE

  // ---- store: nb 0..3 -> q, 4..7 -> k, 8..11 -> v (transposed per 64-chunk)
  #pragma unroll
  for (int g = 0; g < 2; ++g) {
    int rb = r0 + g * 16;
    #pragma unroll
    for (int j = 0; j < 3; ++j) {
      int nb = cq * 3 + j;
      if (nb < 8) {
        unsigned short* dst = (nb < 4) ? q_ws : k_ws;
        int c = (nb & 3) * 16 + rl;
        #pragma unroll
        for (int r = 0; r < 4; ++r) {
          int row = rb + hi * 4 + r;
          dst[(size_t)row * HS + c] = f2b(acc[g][j][r]);
        }
      } else {
        int ch   = rb >> 6;
        int key0 = (rb & 63) + hi * 4;
        int d = (nb - 8) * 16 + rl;
        unsigned u0 = (unsigned)f2b(acc[g][j][0]) | ((unsigned)f2b(acc[g][j][1]) << 16);
        unsigned u1 = (unsigned)f2b(acc[g][j][2]) | ((unsigned)f2b(acc[g][j][3]) << 16);
        uint2 uu; uu.x = u0; uu.y = u1;
        *(uint2*)(vt_ws + (size_t)ch * 4096 + d * 64 + key0) = uu;
      }
    }
  }
}

// ---------------- Sliding-window flash attention via MFMA ----------------
// grid 256 blocks (b, 64-q tile) x 256 threads (4 waves, 16 q-rows each).
// Swapped QK^T (S^T = K @ Q^T) -> softmax lane-local; P via wave-private LDS;
// PV with V^T staged swizzled.
__global__ __launch_bounds__(256) void attn_mfma_kernel(
    const unsigned short* __restrict__ q_ws, const unsigned short* __restrict__ k_ws,
    const unsigned short* __restrict__ vt_ws, float* __restrict__ out)
{
  __shared__ uint4 smem4[1600];                 // 25600 B
  unsigned char* smem = (unsigned char*)smem4;  // K:[0,8K) Vt:[8K,16K) P:16K+

  const int tid = threadIdx.x;
  const int l   = tid & 63;
  const int wid = tid >> 6;
  const int rl  = l & 15;
  const int hi  = l >> 4;
  const int b   = blockIdx.x >> 6;
  const int qt  = blockIdx.x & 63;
  const int t0  = qt * 64;
  const int t0w = t0 + wid * 16;

  // Q B-fragments (held in registers): lane = q row t0w+rl, d = hi*8+j (+32)
  const unsigned short* qrow = q_ws + (size_t)(b * TT + t0w + rl) * HS;
  bf16x8 qb0 = *(const bf16x8*)(qrow + hi * 8);
  bf16x8 qb1 = *(const bf16x8*)(qrow + 32 + hi * 8);

  f32x4 oacc[4];
  #pragma unroll
  for (int i = 0; i < 4; ++i) oacc[i] = (f32x4){0.f, 0.f, 0.f, 0.f};
  float m_run = -INFINITY, l_run = 0.f;

  int s_lo = t0 - WIN; if (s_lo < 0) s_lo = 0;
  unsigned char* pbase = smem + 16384 + wid * 2304 + rl * 144;

  for (int sc = s_lo; sc < t0 + 64; sc += 64) {
    __syncthreads();
    // ---- stage K and Vt chunk (64x64 bf16 each), XOR-swizzled rows ----
    {
      const unsigned short* kg = k_ws + (size_t)(b * TT + sc) * HS;
      const unsigned short* vg = vt_ws + (size_t)((b * TT + sc) >> 6) * 4096;
      #pragma unroll
      for (int i = 0; i < 2; ++i) {
        int idx = tid + i * 256;
        int row = idx >> 3;
        int c16 = idx & 7;
        uint4 kv = *(const uint4*)(kg + row * 64 + c16 * 8);
        uint4 vv = *(const uint4*)(vg + row * 64 + c16 * 8);
        *(uint4*)(smem + row * 128 + ((c16 ^ (row & 7)) * 16)) = kv;
        *(uint4*)(smem + 8192 + row * 128 + ((c16 ^ (row & 7)) * 16)) = vv;
      }
    }
    __syncthreads();

    // ---- S^T = K @ Q^T : 4 key-block fragments ----
    f32x4 sacc[4];
    #pragma unroll
    for (int i = 0; i < 4; ++i) sacc[i] = (f32x4){0.f, 0.f, 0.f, 0.f};
    #pragma unroll
    for (int kb = 0; kb < 4; ++kb) {
      int row = kb * 16 + rl;
      unsigned char* kr = smem + row * 128;
      bf16x8 k0 = *(const bf16x8*)(kr + (((hi) ^ (row & 7)) * 16));
      bf16x8 k1 = *(const bf16x8*)(kr + (((4 + hi) ^ (row & 7)) * 16));
      sacc[kb] = MFMA16(k0, qb0, sacc[kb]);
      sacc[kb] = MFMA16(k1, qb1, sacc[kb]);
    }

    // ---- mask + scale + online softmax (lane owns one q = t0w+rl) ----
    const int tg = t0w + rl;
    float p[16];
    float tm = -INFINITY;
    bool full = (sc + 63 <= t0w) && (sc >= t0w - 496);
    #pragma unroll
    for (int kb = 0; kb < 4; ++kb)
      #pragma unroll
      for (int r = 0; r < 4; ++r) {
        float v = sacc[kb][r] * 0.125f;
        if (!full) {
          int key = sc + kb * 16 + hi * 4 + r;
          int diff = tg - key;
          v = (diff >= 0 && diff < WIN) ? v : -INFINITY;
        }
        p[kb * 4 + r] = v;
        tm = fmaxf(tm, v);
      }
    tm = fmaxf(tm, __shfl_xor(tm, 16));
    tm = fmaxf(tm, __shfl_xor(tm, 32));
    float m_new = fmaxf(m_run, tm);
    float fac  = (m_new == -INFINITY) ? 1.f : __expf(m_run - m_new);
    float msub = (m_new == -INFINITY) ? 0.f : m_new;
    float lsum = 0.f;
    #pragma unroll
    for (int i = 0; i < 16; ++i) { p[i] = __expf(p[i] - msub); lsum += p[i]; }
    lsum += __shfl_xor(lsum, 16);
    lsum += __shfl_xor(lsum, 32);
    l_run = l_run * fac + lsum;
    m_run = m_new;

    // ---- P -> wave-private LDS (row q=rl, stride 144 B) ----
    #pragma unroll
    for (int kb = 0; kb < 4; ++kb) {
      unsigned u0 = (unsigned)f2b(p[kb * 4 + 0]) | ((unsigned)f2b(p[kb * 4 + 1]) << 16);
      unsigned u1 = (unsigned)f2b(p[kb * 4 + 2]) | ((unsigned)f2b(p[kb * 4 + 3]) << 16);
      uint2 uu; uu.x = u0; uu.y = u1;
      *(uint2*)(pbase + kb * 32 + hi * 8) = uu;
    }

    // ---- rescale O by fac (redistribute to PV C-layout q = hi*4+r) ----
    #pragma unroll
    for (int r = 0; r < 4; ++r) {
      float fr = __shfl(fac, (l & 48) | (hi * 4 + r));
      oacc[0][r] *= fr; oacc[1][r] *= fr; oacc[2][r] *= fr; oacc[3][r] *= fr;
    }

    // ---- PV: O[q][d] += P @ V ----
    bf16x8 pa0 = *(const bf16x8*)(pbase + hi * 16);
    bf16x8 pa1 = *(const bf16x8*)(pbase + 64 + hi * 16);
    #pragma unroll
    for (int f = 0; f < 4; ++f) {
      int d = f * 16 + rl;
      unsigned char* vr = smem + 8192 + d * 128;
      bf16x8 v0 = *(const bf16x8*)(vr + (((hi) ^ (d & 7)) * 16));
      bf16x8 v1 = *(const bf16x8*)(vr + (((4 + hi) ^ (d & 7)) * 16));
      oacc[f] = MFMA16(pa0, v0, oacc[f]);
      oacc[f] = MFMA16(pa1, v1, oacc[f]);
    }
  }

  // ---- epilogue: normalize and store f32 ----
  float inv = 1.f / l_run;   // softmax layout (q = rl)
  #pragma unroll
  for (int r = 0; r < 4; ++r) {
    float ir = __shfl(inv, (l & 48) | (hi * 4 + r));
    int row = b * TT + t0w + hi * 4 + r;
    #pragma unroll
    for (int f = 0; f < 4; ++f)
      out[(size_t)row * HS + f * 16 + rl] = oacc[f][r] * ir;
  }
}

extern "C" void kernel_launch(void* const* d_in, const int* in_sizes, int n_in,
                              void* d_out, int out_size, void* d_ws, size_t ws_size,
                              hipStream_t stream) {
  // setup_inputs dict order: x, w_key, w_query, w_value
  const float* x  = (const float*)d_in[0];
  const float* wk = (const float*)d_in[1];
  const float* wq = (const float*)d_in[2];
  const float* wv = (const float*)d_in[3];
  float* out = (float*)d_out;

  unsigned short* wp    = (unsigned short*)d_ws;        // 196608 el = 384 KB
  unsigned short* q_ws  = wp + 196608;                  // 2 MB
  unsigned short* k_ws  = q_ws + (size_t)NROW * HS;     // 2 MB
  unsigned short* vt_ws = k_ws + (size_t)NROW * HS;     // 2 MB

  pack_w_kernel<<<192, 256, 0, stream>>>(wq, wk, wv, wp);
  proj_mfma_kernel<<<NROW / 32, 256, 0, stream>>>(x, wp, q_ws, k_ws, vt_ws);
  attn_mfma_kernel<<<BB * (TT / 64), 256, 0, stream>>>(q_ws, k_ws, vt_ws, out);
}

// Round 7
// 46.297 us; speedup vs baseline: 1.1884x; 1.0181x over previous
//
#include <hip/hip_runtime.h>
#include <hip/hip_bf16.h>
#include <math.h>

#define BB 4
#define TT 4096
#define CC 1024
#define HS 64
#define WIN 512
#define NROW (BB*TT)

typedef float f32x4 __attribute__((ext_vector_type(4)));
typedef short bf16x8 __attribute__((ext_vector_type(8)));

#define MFMA16(a, b, c) __builtin_amdgcn_mfma_f32_16x16x32_bf16((a), (b), (c), 0, 0, 0)

#define GLOAD_LDS(gp, lp) __builtin_amdgcn_global_load_lds( \
    (const __attribute__((address_space(1))) void*)(gp), \
    (__attribute__((address_space(3))) void*)(lp), 16, 0, 0)

__device__ inline unsigned short f2b(float f) {
  union { __hip_bfloat16 h; unsigned short u; } v;
  v.h = __float2bfloat16(f);   // HW RNE convert
  return v.u;
}

// ---------------- pack W into MFMA B-fragment order (bf16) ----------------
// wp flat index: ((kt*12 + nb)*64 + lane)*8 + j
// holds W[k = kt*32 + (lane>>4)*8 + j][n = nb*16 + (lane&15)],
// n: 0..63 = w_query, 64..127 = w_key, 128..191 = w_value
__global__ __launch_bounds__(256) void pack_w_kernel(
    const float* __restrict__ wq, const float* __restrict__ wk,
    const float* __restrict__ wv, unsigned short* __restrict__ wp)
{
  int t = blockIdx.x * 256 + threadIdx.x;   // 49152 threads
  int kg = t / 48;                          // 0..1023  (k index)
  int nq = t % 48;                          // 4-col group
  int n0 = nq * 4;
  int m  = n0 >> 6;
  int c  = n0 & 63;
  const float* w = (m == 0) ? wq : (m == 1) ? wk : wv;
  float4 v = *(const float4*)&w[(size_t)kg * HS + c];
  int kt = kg >> 5;
  int hi = (kg >> 3) & 3;
  int j  = kg & 7;
  float vals[4] = {v.x, v.y, v.z, v.w};
  #pragma unroll
  for (int i = 0; i < 4; ++i) {
    int n  = n0 + i;
    int nb = n >> 4;
    int rl = n & 15;
    int lane = hi * 16 + rl;
    wp[((size_t)(kt * 12 + nb) * 64 + lane) * 8 + j] = f2b(vals[i]);
  }
}

// ---------------- Projection via MFMA: [q|k|v] = x @ W ----------------
// LDS-staged GEMM with counted-vmcnt 2-deep pipeline (T3/T4): never drain
// vmcnt to 0 in the main loop; raw s_barrier (no __syncthreads drain).
// 512 blocks x 256 threads (4 waves). Block = 32 rows x 192 cols; wave cq
// owns 32 rows x 48 cols (3 nb). 16 K-steps of BK=64.
__global__ __launch_bounds__(256) void proj_mfma_kernel(
    const float* __restrict__ x, const unsigned short* __restrict__ wp,
    unsigned short* __restrict__ q_ws, unsigned short* __restrict__ k_ws,
    unsigned short* __restrict__ vt_ws)
{
  __shared__ unsigned char xbuf[2][8192];    // [buf][slot(512)*16B]
  __shared__ unsigned char wbuf[2][24576];   // [buf][slot(1536)*16B]

  const int tid = threadIdx.x;
  const int l   = tid & 63;
  const int cq  = tid >> 6;     // wave = col quarter (3 nb)
  const int rl  = l & 15;
  const int hi  = l >> 4;
  const int r0  = blockIdx.x * 32;

  f32x4 acc[2][3];
  #pragma unroll
  for (int g = 0; g < 2; ++g)
    #pragma unroll
    for (int j = 0; j < 3; ++j) acc[g][j] = (f32x4){0.f, 0.f, 0.f, 0.f};

  // staging (8 VMEM ops/thread/step): x slot s: row/col per decode below;
  // W slot t: straight fragment stream.
#define STAGE(KS, BUF) { \
    _Pragma("unroll") \
    for (int r = 0; r < 2; ++r) { \
      int s  = r * 256 + tid; \
      int h2 = s & 1; \
      int lq = (s >> 1) & 63; \
      int f  = s >> 7; \
      int row = r0 + (f & 1) * 16 + (lq & 15); \
      int col = (KS) * 64 + (f >> 1) * 32 + (lq >> 4) * 8 + h2 * 4; \
      GLOAD_LDS(x + (size_t)row * CC + col, &xbuf[BUF][s * 16]); \
    } \
    const unsigned short* wsrc = wp + (size_t)(KS) * 12288; \
    _Pragma("unroll") \
    for (int r = 0; r < 6; ++r) { \
      int t = r * 256 + tid; \
      GLOAD_LDS(wsrc + t * 8, &wbuf[BUF][t * 16]); \
    } }

  STAGE(0, 0)
  STAGE(1, 1)

  for (int ks = 0; ks < 16; ++ks) {
    const int cur = ks & 1;
    // buf[cur]'s 8 loads are the oldest; keep the other buffer's 8 in flight.
    if (ks < 15) { asm volatile("s_waitcnt vmcnt(8)" ::: "memory"); }
    else         { asm volatile("s_waitcnt vmcnt(0)" ::: "memory"); }
    __builtin_amdgcn_sched_barrier(0);
    __builtin_amdgcn_s_barrier();

    // ---- compute from buffers[cur] ----
    #pragma unroll
    for (int ktl = 0; ktl < 2; ++ktl) {
      bf16x8 afr[2];
      #pragma unroll
      for (int g = 0; g < 2; ++g) {
        const float* ap = (const float*)&xbuf[cur][(((ktl * 2 + g) * 64 + l) * 32)];
        f32x4 a0 = *(const f32x4*)ap;
        f32x4 a1 = *(const f32x4*)(ap + 4);
        bf16x8 af;
        af[0] = (short)f2b(a0[0]); af[1] = (short)f2b(a0[1]);
        af[2] = (short)f2b(a0[2]); af[3] = (short)f2b(a0[3]);
        af[4] = (short)f2b(a1[0]); af[5] = (short)f2b(a1[1]);
        af[6] = (short)f2b(a1[2]); af[7] = (short)f2b(a1[3]);
        afr[g] = af;
      }
      #pragma unroll
      for (int j = 0; j < 3; ++j) {
        bf16x8 wf = *(const bf16x8*)&wbuf[cur][((ktl * 12 + cq * 3 + j) * 64 + l) * 16];
        acc[0][j] = MFMA16(afr[0], wf, acc[0][j]);
        acc[1][j] = MFMA16(afr[1], wf, acc[1][j]);
      }
    }

    if (ks < 14) {
      // WAR guard: my LDS reads done, then all waves done, then overwrite.
      asm volatile("s_waitcnt lgkmcnt(0)" ::: "memory");
      __builtin_amdgcn_sched_barrier(0);
      __builtin_amdgcn_s_barrier();
      STAGE(ks + 2, cur)
    }
  }
#undef STAGE

  // ---- store: nb 0..3 -> q, 4..7 -> k, 8..11 -> v (transposed per 64-chunk)
  #pragma unroll
  for (int g = 0; g < 2; ++g) {
    int rb = r0 + g * 16;
    #pragma unroll
    for (int j = 0; j < 3; ++j) {
      int nb = cq * 3 + j;
      if (nb < 8) {
        unsigned short* dst = (nb < 4) ? q_ws : k_ws;
        int c = (nb & 3) * 16 + rl;
        #pragma unroll
        for (int r = 0; r < 4; ++r) {
          int row = rb + hi * 4 + r;
          dst[(size_t)row * HS + c] = f2b(acc[g][j][r]);
        }
      } else {
        int ch   = rb >> 6;
        int key0 = (rb & 63) + hi * 4;
        int d = (nb - 8) * 16 + rl;
        unsigned u0 = (unsigned)f2b(acc[g][j][0]) | ((unsigned)f2b(acc[g][j][1]) << 16);
        unsigned u1 = (unsigned)f2b(acc[g][j][2]) | ((unsigned)f2b(acc[g][j][3]) << 16);
        uint2 uu; uu.x = u0; uu.y = u1;
        *(uint2*)(vt_ws + (size_t)ch * 4096 + d * 64 + key0) = uu;
      }
    }
  }
}

// ---------------- Sliding-window flash attention via MFMA ----------------
// grid 256 blocks (b, 64-q tile) x 256 threads (4 waves, 16 q-rows each).
// Swapped QK^T (S^T = K @ Q^T) -> softmax lane-local; P via wave-private LDS;
// PV with V^T staged swizzled.
__global__ __launch_bounds__(256) void attn_mfma_kernel(
    const unsigned short* __restrict__ q_ws, const unsigned short* __restrict__ k_ws,
    const unsigned short* __restrict__ vt_ws, float* __restrict__ out)
{
  __shared__ uint4 smem4[1600];                 // 25600 B
  unsigned char* smem = (unsigned char*)smem4;  // K:[0,8K) Vt:[8K,16K) P:16K+

  const int tid = threadIdx.x;
  const int l   = tid & 63;
  const int wid = tid >> 6;
  const int rl  = l & 15;
  const int hi  = l >> 4;
  const int b   = blockIdx.x >> 6;
  const int qt  = blockIdx.x & 63;
  const int t0  = qt * 64;
  const int t0w = t0 + wid * 16;

  // Q B-fragments (held in registers): lane = q row t0w+rl, d = hi*8+j (+32)
  const unsigned short* qrow = q_ws + (size_t)(b * TT + t0w + rl) * HS;
  bf16x8 qb0 = *(const bf16x8*)(qrow + hi * 8);
  bf16x8 qb1 = *(const bf16x8*)(qrow + 32 + hi * 8);

  f32x4 oacc[4];
  #pragma unroll
  for (int i = 0; i < 4; ++i) oacc[i] = (f32x4){0.f, 0.f, 0.f, 0.f};
  float m_run = -INFINITY, l_run = 0.f;

  int s_lo = t0 - WIN; if (s_lo < 0) s_lo = 0;
  unsigned char* pbase = smem + 16384 + wid * 2304 + rl * 144;

  for (int sc = s_lo; sc < t0 + 64; sc += 64) {
    __syncthreads();
    // ---- stage K and Vt chunk (64x64 bf16 each), XOR-swizzled rows ----
    {
      const unsigned short* kg = k_ws + (size_t)(b * TT + sc) * HS;
      const unsigned short* vg = vt_ws + (size_t)((b * TT + sc) >> 6) * 4096;
      #pragma unroll
      for (int i = 0; i < 2; ++i) {
        int idx = tid + i * 256;
        int row = idx >> 3;
        int c16 = idx & 7;
        uint4 kv = *(const uint4*)(kg + row * 64 + c16 * 8);
        uint4 vv = *(const uint4*)(vg + row * 64 + c16 * 8);
        *(uint4*)(smem + row * 128 + ((c16 ^ (row & 7)) * 16)) = kv;
        *(uint4*)(smem + 8192 + row * 128 + ((c16 ^ (row & 7)) * 16)) = vv;
      }
    }
    __syncthreads();

    // ---- S^T = K @ Q^T : 4 key-block fragments ----
    f32x4 sacc[4];
    #pragma unroll
    for (int i = 0; i < 4; ++i) sacc[i] = (f32x4){0.f, 0.f, 0.f, 0.f};
    #pragma unroll
    for (int kb = 0; kb < 4; ++kb) {
      int row = kb * 16 + rl;
      unsigned char* kr = smem + row * 128;
      bf16x8 k0 = *(const bf16x8*)(kr + (((hi) ^ (row & 7)) * 16));
      bf16x8 k1 = *(const bf16x8*)(kr + (((4 + hi) ^ (row & 7)) * 16));
      sacc[kb] = MFMA16(k0, qb0, sacc[kb]);
      sacc[kb] = MFMA16(k1, qb1, sacc[kb]);
    }

    // ---- mask + scale + online softmax (lane owns one q = t0w+rl) ----
    const int tg = t0w + rl;
    float p[16];
    float tm = -INFINITY;
    bool full = (sc + 63 <= t0w) && (sc >= t0w - 496);
    #pragma unroll
    for (int kb = 0; kb < 4; ++kb)
      #pragma unroll
      for (int r = 0; r < 4; ++r) {
        float v = sacc[kb][r] * 0.125f;
        if (!full) {
          int key = sc + kb * 16 + hi * 4 + r;
          int diff = tg - key;
          v = (diff >= 0 && diff < WIN) ? v : -INFINITY;
        }
        p[kb * 4 + r] = v;
        tm = fmaxf(tm, v);
      }
    tm = fmaxf(tm, __shfl_xor(tm, 16));
    tm = fmaxf(tm, __shfl_xor(tm, 32));
    float m_new = fmaxf(m_run, tm);
    float fac  = (m_new == -INFINITY) ? 1.f : __expf(m_run - m_new);
    float msub = (m_new == -INFINITY) ? 0.f : m_new;
    float lsum = 0.f;
    #pragma unroll
    for (int i = 0; i < 16; ++i) { p[i] = __expf(p[i] - msub); lsum += p[i]; }
    lsum += __shfl_xor(lsum, 16);
    lsum += __shfl_xor(lsum, 32);
    l_run = l_run * fac + lsum;
    m_run = m_new;

    // ---- P -> wave-private LDS (row q=rl, stride 144 B) ----
    #pragma unroll
    for (int kb = 0; kb < 4; ++kb) {
      unsigned u0 = (unsigned)f2b(p[kb * 4 + 0]) | ((unsigned)f2b(p[kb * 4 + 1]) << 16);
      unsigned u1 = (unsigned)f2b(p[kb * 4 + 2]) | ((unsigned)f2b(p[kb * 4 + 3]) << 16);
      uint2 uu; uu.x = u0; uu.y = u1;
      *(uint2*)(pbase + kb * 32 + hi * 8) = uu;
    }

    // ---- rescale O by fac (redistribute to PV C-layout q = hi*4+r) ----
    #pragma unroll
    for (int r = 0; r < 4; ++r) {
      float fr = __shfl(fac, (l & 48) | (hi * 4 + r));
      oacc[0][r] *= fr; oacc[1][r] *= fr; oacc[2][r] *= fr; oacc[3][r] *= fr;
    }

    // ---- PV: O[q][d] += P @ V ----
    bf16x8 pa0 = *(const bf16x8*)(pbase + hi * 16);
    bf16x8 pa1 = *(const bf16x8*)(pbase + 64 + hi * 16);
    #pragma unroll
    for (int f = 0; f < 4; ++f) {
      int d = f * 16 + rl;
      unsigned char* vr = smem + 8192 + d * 128;
      bf16x8 v0 = *(const bf16x8*)(vr + (((hi) ^ (d & 7)) * 16));
      bf16x8 v1 = *(const bf16x8*)(vr + (((4 + hi) ^ (d & 7)) * 16));
      oacc[f] = MFMA16(pa0, v0, oacc[f]);
      oacc[f] = MFMA16(pa1, v1, oacc[f]);
    }
  }

  // ---- epilogue: normalize and store f32 ----
  float inv = 1.f / l_run;   // softmax layout (q = rl)
  #pragma unroll
  for (int r = 0; r < 4; ++r) {
    float ir = __shfl(inv, (l & 48) | (hi * 4 + r));
    int row = b * TT + t0w + hi * 4 + r;
    #pragma unroll
    for (int f = 0; f < 4; ++f)
      out[(size_t)row * HS + f * 16 + rl] = oacc[f][r] * ir;
  }
}

extern "C" void kernel_launch(void* const* d_in, const int* in_sizes, int n_in,
                              void* d_out, int out_size, void* d_ws, size_t ws_size,
                              hipStream_t stream) {
  // setup_inputs dict order: x, w_key, w_query, w_value
  const float* x  = (const float*)d_in[0];
  const float* wk = (const float*)d_in[1];
  const float* wq = (const float*)d_in[2];
  const float* wv = (const float*)d_in[3];
  float* out = (float*)d_out;

  unsigned short* wp    = (unsigned short*)d_ws;        // 196608 el = 384 KB
  unsigned short* q_ws  = wp + 196608;                  // 2 MB
  unsigned short* k_ws  = q_ws + (size_t)NROW * HS;     // 2 MB
  unsigned short* vt_ws = k_ws + (size_t)NROW * HS;     // 2 MB

  pack_w_kernel<<<192, 256, 0, stream>>>(wq, wk, wv, wp);
  proj_mfma_kernel<<<NROW / 32, 256, 0, stream>>>(x, wp, q_ws, k_ws, vt_ws);
  attn_mfma_kernel<<<BB * (TT / 64), 256, 0, stream>>>(q_ws, k_ws, vt_ws, out);
}